// Round 1
// baseline (1087.887 us; speedup 1.0000x reference)
//
#include <hip/hip_runtime.h>
#include <math.h>

#define VOCAB 8000
#define BATCH 128
#define TMAX  512
#define DIM   256
#define HID   128
#define G4    512     // 4*HID
#define NCOL  1024    // 2*G4 (both directions)

// ---------------------------------------------------------------------------
// Kernel 1: embW[v][n] = emb[v,:] . W_ih_dir[n,:] + b_ih_dir[n] + b_hh_dir[n]
//   n in [0,512)  -> forward dir, n in [512,1024) -> backward dir
//   fp32 tiled GEMM: 128x128 tile, 256 threads, 8x8 micro-tile, K-chunk 32
// ---------------------------------------------------------------------------
__global__ __launch_bounds__(256) void embw_gemm(
    const float* __restrict__ emb,
    const float* __restrict__ Wf, const float* __restrict__ Wb,
    const float* __restrict__ bihf, const float* __restrict__ bhhf,
    const float* __restrict__ bihb, const float* __restrict__ bhhb,
    float* __restrict__ embW) {
  __shared__ float As[32][132];   // k-major, padded stride (16B aligned rows)
  __shared__ float Bs[32][132];
  const int tid = threadIdx.x;
  const int m0 = blockIdx.x * 128;
  const int n0 = blockIdx.y * 128;
  const int tx = tid & 15, ty = tid >> 4;
  const int lrow = tid >> 1;            // 0..127
  const int lseg = (tid & 1) * 16;      // 0 or 16 (k offset)
  const float* Wsrc = (n0 < 512) ? Wf : Wb;
  const int nbase = (n0 < 512) ? n0 : (n0 - 512);

  float acc[8][8];
  #pragma unroll
  for (int i = 0; i < 8; ++i)
    #pragma unroll
    for (int jj = 0; jj < 8; ++jj) acc[i][jj] = 0.f;

  for (int k0 = 0; k0 < 256; k0 += 32) {
    const int gm = m0 + lrow;
    #pragma unroll
    for (int q = 0; q < 4; ++q) {
      float4 v = make_float4(0.f, 0.f, 0.f, 0.f);
      if (gm < VOCAB) v = *(const float4*)(emb + (size_t)gm * 256 + k0 + lseg + 4 * q);
      As[lseg + 4*q + 0][lrow] = v.x;
      As[lseg + 4*q + 1][lrow] = v.y;
      As[lseg + 4*q + 2][lrow] = v.z;
      As[lseg + 4*q + 3][lrow] = v.w;
    }
    #pragma unroll
    for (int q = 0; q < 4; ++q) {
      float4 v = *(const float4*)(Wsrc + (size_t)(nbase + lrow) * 256 + k0 + lseg + 4 * q);
      Bs[lseg + 4*q + 0][lrow] = v.x;
      Bs[lseg + 4*q + 1][lrow] = v.y;
      Bs[lseg + 4*q + 2][lrow] = v.z;
      Bs[lseg + 4*q + 3][lrow] = v.w;
    }
    __syncthreads();
    #pragma unroll
    for (int k = 0; k < 32; ++k) {
      // a: rows ty*8..+7 (broadcast across tx); b: cols split tx*4 and 64+tx*4
      float4 av0 = *(const float4*)&As[k][ty * 8];
      float4 av1 = *(const float4*)&As[k][ty * 8 + 4];
      float4 bv0 = *(const float4*)&Bs[k][tx * 4];
      float4 bv1 = *(const float4*)&Bs[k][64 + tx * 4];
      float a[8]  = {av0.x, av0.y, av0.z, av0.w, av1.x, av1.y, av1.z, av1.w};
      float bb[8] = {bv0.x, bv0.y, bv0.z, bv0.w, bv1.x, bv1.y, bv1.z, bv1.w};
      #pragma unroll
      for (int i = 0; i < 8; ++i)
        #pragma unroll
        for (int jj = 0; jj < 8; ++jj)
          acc[i][jj] += a[i] * bb[jj];
    }
    __syncthreads();
  }

  float bias[8];
  #pragma unroll
  for (int jj = 0; jj < 8; ++jj) {
    int n = n0 + ((jj < 4) ? (tx * 4 + jj) : (64 + tx * 4 + (jj - 4)));
    bias[jj] = (n < 512) ? (bihf[n] + bhhf[n]) : (bihb[n - 512] + bhhb[n - 512]);
  }
  #pragma unroll
  for (int i = 0; i < 8; ++i) {
    int gm = m0 + ty * 8 + i;
    if (gm >= VOCAB) continue;
    float4 v0 = make_float4(acc[i][0] + bias[0], acc[i][1] + bias[1],
                            acc[i][2] + bias[2], acc[i][3] + bias[3]);
    float4 v1 = make_float4(acc[i][4] + bias[4], acc[i][5] + bias[5],
                            acc[i][6] + bias[6], acc[i][7] + bias[7]);
    *(float4*)(embW + (size_t)gm * NCOL + n0 + tx * 4) = v0;
    *(float4*)(embW + (size_t)gm * NCOL + n0 + 64 + tx * 4) = v1;
  }
}

// ---------------------------------------------------------------------------
// Kernel 2: masked LSTM recurrence. One block per (seq, dir); 256 blocks total
// (1 per CU). Thread j owns gate j; W_hh row j held in 128 VGPRs.
// h broadcast via LDS; 2 barriers per step; h written to global for Viterbi.
// ---------------------------------------------------------------------------
__global__ __launch_bounds__(512, 2) void lstm_rec(
    const int* __restrict__ pad_seq, const int* __restrict__ lens,
    const float* __restrict__ Whh_f, const float* __restrict__ Whh_b,
    const float* __restrict__ embW, float* __restrict__ h_out) {
  const int dir = blockIdx.x & 1;
  const int b = blockIdx.x >> 1;
  const int j = threadIdx.x;
  __shared__ float h_buf[HID];
  __shared__ float gates[G4];
  __shared__ int tok[TMAX];

  tok[j] = pad_seq[b * TMAX + j];
  if (j < HID) h_buf[j] = 0.f;
  const int len = lens[b];
  const float* __restrict__ Whh = dir ? Whh_b : Whh_f;

  float w[128];
  {
    const float4* wr = (const float4*)(Whh + (size_t)j * HID);
    #pragma unroll
    for (int k = 0; k < 32; ++k) {
      float4 v = wr[k];
      w[4*k + 0] = v.x; w[4*k + 1] = v.y; w[4*k + 2] = v.z; w[4*k + 3] = v.w;
    }
  }
  float c = 0.f;
  __syncthreads();

  const float* __restrict__ ecol = embW + dir * G4 + j;
  const int tstep = dir ? -1 : 1;
  int t = dir ? (len - 1) : 0;
  float xw = ecol[(size_t)tok[t] * NCOL];   // includes folded biases

  for (int s = 0; s < len; ++s) {
    const float xcur = xw;
    const int tn = t + tstep;
    if (s + 1 < len) xw = ecol[(size_t)tok[tn] * NCOL];  // prefetch next token row

    float a0 = xcur, a1 = 0.f, a2 = 0.f, a3 = 0.f;
    const float4* h4 = (const float4*)h_buf;
    #pragma unroll
    for (int kk = 0; kk < 32; ++kk) {
      float4 hv = h4[kk];                   // ds_read_b128 broadcast
      a0 += hv.x * w[4*kk + 0];
      a1 += hv.y * w[4*kk + 1];
      a2 += hv.z * w[4*kk + 2];
      a3 += hv.w * w[4*kk + 3];
    }
    gates[j] = (a0 + a1) + (a2 + a3);
    __syncthreads();

    if (j < HID) {
      const float gi = gates[j];
      const float gf = gates[j + HID];
      const float gg = gates[j + 2 * HID];
      const float go = gates[j + 3 * HID];
      const float ig = 1.f / (1.f + expf(-gi));
      const float fg = 1.f / (1.f + expf(-gf));
      const float og = 1.f / (1.f + expf(-go));
      c = fg * c + ig * tanhf(gg);
      const float h = og * tanhf(c);
      h_buf[j] = h;
      h_out[((size_t)(b * TMAX + t)) * DIM + dir * HID + j] = h;
    }
    __syncthreads();
    t = tn;
  }
}

// ---------------------------------------------------------------------------
// Kernel 3: emissions + Viterbi DP + backtrace. One block per sequence.
// Phase 1 parallel over t; phases 2/3 serial on thread 0 (scores in LDS).
// ---------------------------------------------------------------------------
__global__ __launch_bounds__(512) void viterbi_k(
    const int* __restrict__ lens, const float* __restrict__ h_out,
    const float* __restrict__ W_lab, const float* __restrict__ b_lab,
    const float* __restrict__ trans, const float* __restrict__ from_BOS,
    const float* __restrict__ to_EOS, int* __restrict__ out) {
  const int b = blockIdx.x;
  const int tid = threadIdx.x;
  __shared__ float sc[TMAX][4];
  __shared__ unsigned btm[TMAX];
  __shared__ float wl[4][256];
  __shared__ int labs[TMAX];
  const int len = lens[b];

  for (int i = tid; i < 1024; i += 512) wl[i >> 8][i & 255] = W_lab[i];
  __syncthreads();

  if (tid < len) {
    const float4* h4 = (const float4*)(h_out + ((size_t)(b * TMAX + tid)) * DIM);
    float s0 = b_lab[0], s1 = b_lab[1], s2 = b_lab[2], s3 = b_lab[3];
    #pragma unroll 8
    for (int k4 = 0; k4 < 64; ++k4) {
      float4 hv = h4[k4];
      float4 w0 = *(const float4*)&wl[0][4 * k4];
      float4 w1 = *(const float4*)&wl[1][4 * k4];
      float4 w2 = *(const float4*)&wl[2][4 * k4];
      float4 w3 = *(const float4*)&wl[3][4 * k4];
      s0 += hv.x * w0.x + hv.y * w0.y + hv.z * w0.z + hv.w * w0.w;
      s1 += hv.x * w1.x + hv.y * w1.y + hv.z * w1.z + hv.w * w1.w;
      s2 += hv.x * w2.x + hv.y * w2.y + hv.z * w2.z + hv.w * w2.w;
      s3 += hv.x * w3.x + hv.y * w3.y + hv.z * w3.z + hv.w * w3.w;
    }
    *(float4*)&sc[tid][0] = make_float4(s0, s1, s2, s3);
  }
  __syncthreads();

  if (tid == 0) {
    float tr[16];
    #pragma unroll
    for (int i = 0; i < 16; ++i) tr[i] = trans[i];
    float best[4];
    #pragma unroll
    for (int l = 0; l < 4; ++l) best[l] = from_BOS[l] + sc[0][l];
    for (int ti = 1; ti < len; ++ti) {
      float ee[4] = {sc[ti][0], sc[ti][1], sc[ti][2], sc[ti][3]};
      float nb[4];
      unsigned pk = 0;
      #pragma unroll
      for (int l = 0; l < 4; ++l) {
        // mirror reference add order: best[p] + e[cur] + trans[p][cur]
        float m = best[0] + ee[l] + tr[0 * 4 + l];
        int arg = 0;
        #pragma unroll
        for (int p = 1; p < 4; ++p) {
          float v = best[p] + ee[l] + tr[p * 4 + l];
          if (v > m) { m = v; arg = p; }   // strict > == first-max (np.argmax)
        }
        nb[l] = m;
        pk |= ((unsigned)arg) << (8 * l);
      }
      btm[ti] = pk;
      #pragma unroll
      for (int l = 0; l < 4; ++l) best[l] = nb[l];
    }
    float m = best[0] + to_EOS[0];
    int last = 0;
    #pragma unroll
    for (int l = 1; l < 4; ++l) {
      float v = best[l] + to_EOS[l];
      if (v > m) { m = v; last = l; }
    }
    labs[len - 1] = last;
    int cur = last;
    for (int ti = len - 2; ti >= 0; --ti) {
      cur = (int)((btm[ti + 1] >> (8 * cur)) & 255u);
      labs[ti] = cur;
    }
  }
  __syncthreads();
  out[b * TMAX + tid] = (tid < len) ? labs[tid] : 0;
}

// ---------------------------------------------------------------------------
extern "C" void kernel_launch(void* const* d_in, const int* in_sizes, int n_in,
                              void* d_out, int out_size, void* d_ws, size_t ws_size,
                              hipStream_t stream) {
  const int*   pad_seq  = (const int*)d_in[0];
  const int*   lens     = (const int*)d_in[1];
  const float* emb      = (const float*)d_in[2];
  const float* W_ih_f   = (const float*)d_in[3];
  const float* W_hh_f   = (const float*)d_in[4];
  const float* b_ih_f   = (const float*)d_in[5];
  const float* b_hh_f   = (const float*)d_in[6];
  const float* W_ih_b   = (const float*)d_in[7];
  const float* W_hh_b   = (const float*)d_in[8];
  const float* b_ih_b   = (const float*)d_in[9];
  const float* b_hh_b   = (const float*)d_in[10];
  const float* W_lab    = (const float*)d_in[11];
  const float* b_lab    = (const float*)d_in[12];
  const float* trans    = (const float*)d_in[13];
  const float* from_BOS = (const float*)d_in[14];
  const float* to_EOS   = (const float*)d_in[15];
  int* out = (int*)d_out;

  float* embW  = (float*)d_ws;                       // [8000][1024] fp32 = 32.8 MB
  float* h_out = embW + (size_t)VOCAB * NCOL;        // [B][T][256]  fp32 = 67.1 MB

  embw_gemm<<<dim3(63, 8), 256, 0, stream>>>(emb, W_ih_f, W_ih_b,
                                             b_ih_f, b_hh_f, b_ih_b, b_hh_b, embW);
  lstm_rec<<<dim3(2 * BATCH), 512, 0, stream>>>(pad_seq, lens, W_hh_f, W_hh_b,
                                                embW, h_out);
  viterbi_k<<<dim3(BATCH), 512, 0, stream>>>(lens, h_out, W_lab, b_lab, trans,
                                             from_BOS, to_EOS, out);
}

// Round 2
// 928.916 us; speedup vs baseline: 1.1711x; 1.1711x over previous
//
#include <hip/hip_runtime.h>
#include <math.h>

#define VOCAB 8000
#define BATCH 128
#define TMAX  512
#define DIM   256
#define HID   128
#define G4    512     // 4*HID
#define NCOL  1024    // 2*G4 (both directions)

// ---------------------------------------------------------------------------
// Kernel 1: embW[v][n] = emb[v,:] . W_ih_dir[n,:] + b_ih_dir[n] + b_hh_dir[n]
//   n in [0,512)  -> forward dir, n in [512,1024) -> backward dir
//   fp32 tiled GEMM: 128x128 tile, 256 threads, 8x8 micro-tile, K-chunk 32
// ---------------------------------------------------------------------------
__global__ __launch_bounds__(256) void embw_gemm(
    const float* __restrict__ emb,
    const float* __restrict__ Wf, const float* __restrict__ Wb,
    const float* __restrict__ bihf, const float* __restrict__ bhhf,
    const float* __restrict__ bihb, const float* __restrict__ bhhb,
    float* __restrict__ embW) {
  __shared__ float As[32][132];   // k-major, padded stride
  __shared__ float Bs[32][132];
  const int tid = threadIdx.x;
  const int m0 = blockIdx.x * 128;
  const int n0 = blockIdx.y * 128;
  const int tx = tid & 15, ty = tid >> 4;
  const int lrow = tid >> 1;            // 0..127
  const int lseg = (tid & 1) * 16;      // 0 or 16 (k offset)
  const float* Wsrc = (n0 < 512) ? Wf : Wb;
  const int nbase = (n0 < 512) ? n0 : (n0 - 512);

  float acc[8][8];
  #pragma unroll
  for (int i = 0; i < 8; ++i)
    #pragma unroll
    for (int jj = 0; jj < 8; ++jj) acc[i][jj] = 0.f;

  for (int k0 = 0; k0 < 256; k0 += 32) {
    const int gm = m0 + lrow;
    #pragma unroll
    for (int q = 0; q < 4; ++q) {
      float4 v = make_float4(0.f, 0.f, 0.f, 0.f);
      if (gm < VOCAB) v = *(const float4*)(emb + (size_t)gm * 256 + k0 + lseg + 4 * q);
      As[lseg + 4*q + 0][lrow] = v.x;
      As[lseg + 4*q + 1][lrow] = v.y;
      As[lseg + 4*q + 2][lrow] = v.z;
      As[lseg + 4*q + 3][lrow] = v.w;
    }
    #pragma unroll
    for (int q = 0; q < 4; ++q) {
      float4 v = *(const float4*)(Wsrc + (size_t)(nbase + lrow) * 256 + k0 + lseg + 4 * q);
      Bs[lseg + 4*q + 0][lrow] = v.x;
      Bs[lseg + 4*q + 1][lrow] = v.y;
      Bs[lseg + 4*q + 2][lrow] = v.z;
      Bs[lseg + 4*q + 3][lrow] = v.w;
    }
    __syncthreads();
    #pragma unroll
    for (int k = 0; k < 32; ++k) {
      float4 av0 = *(const float4*)&As[k][ty * 8];
      float4 av1 = *(const float4*)&As[k][ty * 8 + 4];
      float4 bv0 = *(const float4*)&Bs[k][tx * 4];
      float4 bv1 = *(const float4*)&Bs[k][64 + tx * 4];
      float a[8]  = {av0.x, av0.y, av0.z, av0.w, av1.x, av1.y, av1.z, av1.w};
      float bb[8] = {bv0.x, bv0.y, bv0.z, bv0.w, bv1.x, bv1.y, bv1.z, bv1.w};
      #pragma unroll
      for (int i = 0; i < 8; ++i)
        #pragma unroll
        for (int jj = 0; jj < 8; ++jj)
          acc[i][jj] += a[i] * bb[jj];
    }
    __syncthreads();
  }

  float bias[8];
  #pragma unroll
  for (int jj = 0; jj < 8; ++jj) {
    int n = n0 + ((jj < 4) ? (tx * 4 + jj) : (64 + tx * 4 + (jj - 4)));
    bias[jj] = (n < 512) ? (bihf[n] + bhhf[n]) : (bihb[n - 512] + bhhb[n - 512]);
  }
  #pragma unroll
  for (int i = 0; i < 8; ++i) {
    int gm = m0 + ty * 8 + i;
    if (gm >= VOCAB) continue;
    float4 v0 = make_float4(acc[i][0] + bias[0], acc[i][1] + bias[1],
                            acc[i][2] + bias[2], acc[i][3] + bias[3]);
    float4 v1 = make_float4(acc[i][4] + bias[4], acc[i][5] + bias[5],
                            acc[i][6] + bias[6], acc[i][7] + bias[7]);
    *(float4*)(embW + (size_t)gm * NCOL + n0 + tx * 4) = v0;
    *(float4*)(embW + (size_t)gm * NCOL + n0 + 64 + tx * 4) = v1;
  }
}

// ---------------------------------------------------------------------------
// Kernel 2: masked LSTM recurrence. One block per (seq, dir); 256 blocks
// (1 per CU). tid = 4*j + g: gate g of hidden unit j. W_hh row held in 32
// NAMED float4 SSA values (no alloca -> guaranteed VGPRs, no scratch spill).
// Quad shfl_xor exchanges the 4 gate values; c/h computed redundantly per
// quad; h double-buffered in LDS -> exactly ONE __syncthreads per step.
// ---------------------------------------------------------------------------
#define REP32(M) M(0) M(1) M(2) M(3) M(4) M(5) M(6) M(7) M(8) M(9) M(10) \
  M(11) M(12) M(13) M(14) M(15) M(16) M(17) M(18) M(19) M(20) M(21) M(22) \
  M(23) M(24) M(25) M(26) M(27) M(28) M(29) M(30) M(31)

__global__ __launch_bounds__(512, 2) void lstm_rec(
    const int* __restrict__ pad_seq, const int* __restrict__ lens,
    const float* __restrict__ Whh_f, const float* __restrict__ Whh_b,
    const float* __restrict__ embW, float* __restrict__ h_out) {
  const int dir = blockIdx.x & 1;
  const int b = blockIdx.x >> 1;
  const int tid = threadIdx.x;
  const int j = tid >> 2;       // hidden unit 0..127
  const int g = tid & 3;        // gate 0..3 (i,f,g,o)
  __shared__ float h_buf[2][HID];
  __shared__ int tok[TMAX];

  tok[tid] = pad_seq[b * TMAX + tid];
  if (tid < HID) h_buf[0][tid] = 0.f;
  const int len = lens[b];
  const float* __restrict__ Whh = dir ? Whh_b : Whh_f;

  // W_hh row (g*HID + j), 128 floats, in 32 named float4 SSA values
  const float4* wr = (const float4*)(Whh + (size_t)(g * HID + j) * HID);
#define DECLW(i) float4 w##i = wr[i];
  REP32(DECLW)
#undef DECLW

  float c = 0.f;
  __syncthreads();

  const float* __restrict__ ecol = embW + dir * G4 + (g * HID + j);
  const int tstep = dir ? -1 : 1;
  int t = dir ? (len - 1) : 0;
  float xw0 = ecol[(size_t)tok[t] * NCOL];                     // step s
  float xw1 = (len > 1) ? ecol[(size_t)tok[t + tstep] * NCOL] : 0.f;  // s+1

  for (int s = 0; s < len; ++s) {
    // depth-2 prefetch: step s+2 (covers ~900cyc HBM-miss latency)
    float xw2 = 0.f;
    if (s + 2 < len) xw2 = ecol[(size_t)tok[t + 2 * tstep] * NCOL];

    const float4* h4 = (const float4*)h_buf[s & 1];
    float a0 = 0.f, a1 = 0.f, a2 = 0.f, a3 = 0.f;
#define MAC(i) { float4 hv = h4[i];                 \
    a0 = fmaf(hv.x, w##i.x, a0);                    \
    a1 = fmaf(hv.y, w##i.y, a1);                    \
    a2 = fmaf(hv.z, w##i.z, a2);                    \
    a3 = fmaf(hv.w, w##i.w, a3); }
    REP32(MAC)
#undef MAC
    // fold gather in last so the vmcnt wait lands after the FMA stream
    const float a = ((a0 + a1) + (a2 + a3)) + xw0;

    // quad exchange: lane (4j+g) -> all four gate values of unit j
    const float p1 = __shfl_xor(a, 1);    // gate g^1
    const float p2 = __shfl_xor(a, 2);    // gate g^2
    const float p3 = __shfl_xor(p1, 2);   // gate g^3
    const float ev  = (g & 1) ? p1 : a;   // gate (g&~1)
    const float od  = (g & 1) ? a  : p1;  // gate (g&~1)|1
    const float ev2 = (g & 1) ? p3 : p2;  // gate ((g^2)&~1)
    const float od2 = (g & 1) ? p2 : p3;
    const float gi = (g & 2) ? ev2 : ev;
    const float gf = (g & 2) ? od2 : od;
    const float gg = (g & 2) ? ev  : ev2;
    const float go = (g & 2) ? od  : od2;

    const float ig = 1.f / (1.f + expf(-gi));
    const float fg = 1.f / (1.f + expf(-gf));
    const float og = 1.f / (1.f + expf(-go));
    c = fg * c + ig * tanhf(gg);          // redundant x4 per quad, identical
    const float h = og * tanhf(c);

    if (g == 0) {
      h_buf[(s + 1) & 1][j] = h;
      h_out[((size_t)(b * TMAX + t)) * DIM + dir * HID + j] = h;
    }
    __syncthreads();                      // single barrier per step
    xw0 = xw1; xw1 = xw2;
    t += tstep;
  }
}

// ---------------------------------------------------------------------------
// Kernel 3: emissions + Viterbi DP + backtrace. One block per sequence.
// ---------------------------------------------------------------------------
__global__ __launch_bounds__(512) void viterbi_k(
    const int* __restrict__ lens, const float* __restrict__ h_out,
    const float* __restrict__ W_lab, const float* __restrict__ b_lab,
    const float* __restrict__ trans, const float* __restrict__ from_BOS,
    const float* __restrict__ to_EOS, int* __restrict__ out) {
  const int b = blockIdx.x;
  const int tid = threadIdx.x;
  __shared__ float sc[TMAX][4];
  __shared__ unsigned btm[TMAX];
  __shared__ float wl[4][256];
  __shared__ int labs[TMAX];
  const int len = lens[b];

  for (int i = tid; i < 1024; i += 512) wl[i >> 8][i & 255] = W_lab[i];
  __syncthreads();

  if (tid < len) {
    const float4* h4 = (const float4*)(h_out + ((size_t)(b * TMAX + tid)) * DIM);
    float s0 = b_lab[0], s1 = b_lab[1], s2 = b_lab[2], s3 = b_lab[3];
    #pragma unroll 8
    for (int k4 = 0; k4 < 64; ++k4) {
      float4 hv = h4[k4];
      float4 w0 = *(const float4*)&wl[0][4 * k4];
      float4 w1 = *(const float4*)&wl[1][4 * k4];
      float4 w2 = *(const float4*)&wl[2][4 * k4];
      float4 w3 = *(const float4*)&wl[3][4 * k4];
      s0 += hv.x * w0.x + hv.y * w0.y + hv.z * w0.z + hv.w * w0.w;
      s1 += hv.x * w1.x + hv.y * w1.y + hv.z * w1.z + hv.w * w1.w;
      s2 += hv.x * w2.x + hv.y * w2.y + hv.z * w2.z + hv.w * w2.w;
      s3 += hv.x * w3.x + hv.y * w3.y + hv.z * w3.z + hv.w * w3.w;
    }
    *(float4*)&sc[tid][0] = make_float4(s0, s1, s2, s3);
  }
  __syncthreads();

  if (tid == 0) {
    float tr[16];
    #pragma unroll
    for (int i = 0; i < 16; ++i) tr[i] = trans[i];
    float best[4];
    #pragma unroll
    for (int l = 0; l < 4; ++l) best[l] = from_BOS[l] + sc[0][l];
    for (int ti = 1; ti < len; ++ti) {
      float ee[4] = {sc[ti][0], sc[ti][1], sc[ti][2], sc[ti][3]};
      float nb[4];
      unsigned pk = 0;
      #pragma unroll
      for (int l = 0; l < 4; ++l) {
        float m = best[0] + ee[l] + tr[0 * 4 + l];
        int arg = 0;
        #pragma unroll
        for (int p = 1; p < 4; ++p) {
          float v = best[p] + ee[l] + tr[p * 4 + l];
          if (v > m) { m = v; arg = p; }   // strict > == first-max (np.argmax)
        }
        nb[l] = m;
        pk |= ((unsigned)arg) << (8 * l);
      }
      btm[ti] = pk;
      #pragma unroll
      for (int l = 0; l < 4; ++l) best[l] = nb[l];
    }
    float m = best[0] + to_EOS[0];
    int last = 0;
    #pragma unroll
    for (int l = 1; l < 4; ++l) {
      float v = best[l] + to_EOS[l];
      if (v > m) { m = v; last = l; }
    }
    labs[len - 1] = last;
    int cur = last;
    for (int ti = len - 2; ti >= 0; --ti) {
      cur = (int)((btm[ti + 1] >> (8 * cur)) & 255u);
      labs[ti] = cur;
    }
  }
  __syncthreads();
  out[b * TMAX + tid] = (tid < len) ? labs[tid] : 0;
}

// ---------------------------------------------------------------------------
extern "C" void kernel_launch(void* const* d_in, const int* in_sizes, int n_in,
                              void* d_out, int out_size, void* d_ws, size_t ws_size,
                              hipStream_t stream) {
  const int*   pad_seq  = (const int*)d_in[0];
  const int*   lens     = (const int*)d_in[1];
  const float* emb      = (const float*)d_in[2];
  const float* W_ih_f   = (const float*)d_in[3];
  const float* W_hh_f   = (const float*)d_in[4];
  const float* b_ih_f   = (const float*)d_in[5];
  const float* b_hh_f   = (const float*)d_in[6];
  const float* W_ih_b   = (const float*)d_in[7];
  const float* W_hh_b   = (const float*)d_in[8];
  const float* b_ih_b   = (const float*)d_in[9];
  const float* b_hh_b   = (const float*)d_in[10];
  const float* W_lab    = (const float*)d_in[11];
  const float* b_lab    = (const float*)d_in[12];
  const float* trans    = (const float*)d_in[13];
  const float* from_BOS = (const float*)d_in[14];
  const float* to_EOS   = (const float*)d_in[15];
  int* out = (int*)d_out;

  float* embW  = (float*)d_ws;                       // [8000][1024] fp32 = 32.8 MB
  float* h_out = embW + (size_t)VOCAB * NCOL;        // [B][T][256]  fp32 = 67.1 MB

  embw_gemm<<<dim3(63, 8), 256, 0, stream>>>(emb, W_ih_f, W_ih_b,
                                             b_ih_f, b_hh_f, b_ih_b, b_hh_b, embW);
  lstm_rec<<<dim3(2 * BATCH), 512, 0, stream>>>(pad_seq, lens, W_hh_f, W_hh_b,
                                                embW, h_out);
  viterbi_k<<<dim3(BATCH), 512, 0, stream>>>(lens, h_out, W_lab, b_lab, trans,
                                             from_BOS, to_EOS, out);
}